// Round 2
// baseline (1064.223 us; speedup 1.0000x reference)
//
#include <hip/hip_runtime.h>
#include <hip/hip_bf16.h>
#include <stdint.h>

// Problem constants
constexpr int cB = 4, cN = 512, cE = 512, cH = 32, cP = 128;
// D = 16, SCALING = 0.25 folded into Q at projection epilogue.

typedef __attribute__((ext_vector_type(8))) short bf16x8;
typedef __attribute__((ext_vector_type(4))) float f32x4;

__device__ __forceinline__ unsigned short f2bf(float f) {
    union { float f; unsigned u; } v; v.f = f;
    unsigned u = v.u;
    u += 0x7fffu + ((u >> 16) & 1u);   // RNE
    return (unsigned short)(u >> 16);
}
__device__ __forceinline__ float bf2f(unsigned short s) {
    union { unsigned u; float f; } v; v.u = ((unsigned)s) << 16;
    return v.f;
}

// Raw workgroup barrier that does NOT drain vmcnt: LDS writes are fenced via
// lgkmcnt(0); in-flight global loads (register-destined prefetch) stay
// outstanding across the barrier. sched_barrier(0) on both sides per rule #18
// (hipcc hoists register-only ops past inline-asm waitcnt).
__device__ __forceinline__ void barrier_nodrain() {
    asm volatile("s_waitcnt lgkmcnt(0)" ::: "memory");
    __builtin_amdgcn_sched_barrier(0);
    __builtin_amdgcn_s_barrier();
    __builtin_amdgcn_sched_barrier(0);
}

// ---------------- Kernel 1: LayerNorm(query) -> xn (f32) ----------------
__global__ __launch_bounds__(256) void ln_query_kernel(
    const float* __restrict__ q, const float* __restrict__ g,
    const float* __restrict__ b, float* __restrict__ xn)
{
    int row = blockIdx.x;          // 0..B*N-1
    int t = threadIdx.x;           // 256
    const float* xr = q + (size_t)row * cE;
    float2 v = *(const float2*)(xr + t * 2);
    float s = v.x + v.y;
    float ss = v.x * v.x + v.y * v.y;
    #pragma unroll
    for (int o = 32; o > 0; o >>= 1) {
        s  += __shfl_down(s, o, 64);
        ss += __shfl_down(ss, o, 64);
    }
    __shared__ float red[8];
    int wv = t >> 6, ln = t & 63;
    if (ln == 0) { red[wv] = s; red[wv + 4] = ss; }
    __syncthreads();
    if (t == 0) {
        float S = red[0] + red[1] + red[2] + red[3];
        float SS = red[4] + red[5] + red[6] + red[7];
        float mu = S * (1.0f / cE);
        float var = SS * (1.0f / cE) - mu * mu;
        red[0] = mu; red[1] = rsqrtf(var + 1e-5f);
    }
    __syncthreads();
    float mu = red[0], rs = red[1];
    float2 gg = *(const float2*)(g + t * 2);
    float2 bb2 = *(const float2*)(b + t * 2);
    float2 o2;
    o2.x = (v.x - mu) * rs * gg.x + bb2.x;
    o2.y = (v.y - mu) * rs * gg.y + bb2.y;
    *(float2*)(xn + (size_t)row * cE + t * 2) = o2;
}

// ---------------- Kernel 2: setup Wb' (bf16), S_h, cb_h ----------------
__global__ void setup_kernel(
    const float* __restrict__ Wb, const float* __restrict__ pg,
    const float* __restrict__ pb, const float* __restrict__ bbv,
    unsigned short* __restrict__ Wbp, float* __restrict__ Sh,
    float* __restrict__ cbh)
{
    int h = threadIdx.x;
    if (h < cH) {
        float s = 0.f, c = bbv[h];
        for (int p = 0; p < cP; ++p) {
            float wv = Wb[h * cP + p];
            float wp = wv * pg[p];
            s += wp;
            c += pb[p] * wv;
            Wbp[h * cP + p] = f2bf(wp);
        }
        Sh[h] = s; cbh[h] = c;
    }
}

// ------------- Kernel 3: Q/K projections (fp32 GEMM) + w from V tile -------------
__global__ __launch_bounds__(256) void qkv_kernel(
    const float* __restrict__ xn,
    const float* __restrict__ Wq, const float* __restrict__ Wk,
    const float* __restrict__ Wv, const float* __restrict__ Wf,
    float* __restrict__ Q, float* __restrict__ K, float* __restrict__ w)
{
    int mtile = blockIdx.x & 31;      // 32 tiles of 64 rows
    int ntile = blockIdx.x >> 5;      // 24 tiles of 64 cols
    int mat = ntile >> 3;             // 0=Q 1=K 2=V
    int ncol0 = (ntile & 7) * 64;
    const float* W = (mat == 0) ? Wq : ((mat == 1) ? Wk : Wv);
    int rm = mtile * 64;
    int t = threadIdx.x;
    int tm = t >> 4, tn = t & 15;     // 16x16 thread grid, 4x4 micro-tile

    __shared__ float As[32][68];      // [k][m]
    __shared__ float Bs[32][68];      // [k][n]
    float acc[4][4];
    #pragma unroll
    for (int i = 0; i < 4; ++i)
        #pragma unroll
        for (int j = 0; j < 4; ++j) acc[i][j] = 0.f;

    for (int k0 = 0; k0 < cE; k0 += 32) {
        #pragma unroll
        for (int s = 0; s < 2; ++s) {
            int f = t + 256 * s;      // 0..511 float4 slots
            int row = f >> 3, kq = f & 7;
            float4 v = *(const float4*)(xn + (size_t)(rm + row) * cE + k0 + kq * 4);
            As[kq * 4 + 0][row] = v.x; As[kq * 4 + 1][row] = v.y;
            As[kq * 4 + 2][row] = v.z; As[kq * 4 + 3][row] = v.w;
            float4 u = *(const float4*)(W + (size_t)(ncol0 + row) * cE + k0 + kq * 4);
            Bs[kq * 4 + 0][row] = u.x; Bs[kq * 4 + 1][row] = u.y;
            Bs[kq * 4 + 2][row] = u.z; Bs[kq * 4 + 3][row] = u.w;
        }
        __syncthreads();
        #pragma unroll
        for (int kk = 0; kk < 32; ++kk) {
            float a[4], bv[4];
            #pragma unroll
            for (int i = 0; i < 4; ++i) a[i] = As[kk][tm * 4 + i];
            #pragma unroll
            for (int j = 0; j < 4; ++j) bv[j] = Bs[kk][tn * 4 + j];
            #pragma unroll
            for (int i = 0; i < 4; ++i)
                #pragma unroll
                for (int j = 0; j < 4; ++j) acc[i][j] = fmaf(a[i], bv[j], acc[i][j]);
        }
        __syncthreads();
    }

    if (mat < 2) {
        float scale = (mat == 0) ? 0.25f : 1.0f;
        float* dst = (mat == 0) ? Q : K;
        #pragma unroll
        for (int i = 0; i < 4; ++i) {
            int r = rm + tm * 4 + i;
            float4 o;
            o.x = acc[i][0] * scale; o.y = acc[i][1] * scale;
            o.z = acc[i][2] * scale; o.w = acc[i][3] * scale;
            *(float4*)(dst + (size_t)r * cE + ncol0 + tn * 4) = o;
        }
    } else {
        int col0 = ncol0 + tn * 4;
        int h = col0 >> 4;
        float wf[4];
        #pragma unroll
        for (int j = 0; j < 4; ++j) wf[j] = Wf[col0 + j];
        #pragma unroll
        for (int i = 0; i < 4; ++i) {
            int r = rm + tm * 4 + i;
            float part = 0.f;
            #pragma unroll
            for (int j = 0; j < 4; ++j) part = fmaf(acc[i][j], wf[j], part);
            atomicAdd(&w[(size_t)r * cH + h], part);
        }
    }
}

// ------------- Kernel 4: fused bias-GEMM + attention + force (per (b,i)) -------------
// v3: raw barriers (no vmcnt drain) + strict load ordering:
//   A: commit pair tile (waits prefetch regs)  B: issue this-tile w, extract mask,
//   then issue next-tile {mask,pair,dpos} LAST  -> B1 -> stats(shfl)+MFMA -> B2 ->
//   logits (w/mask from regs; K loads in-loop, vmcnt(11) keeps prefetch in flight).
// 2 raw barriers/tile. LDS 36.6 KB -> 4 blocks/CU.
__global__ __launch_bounds__(256, 4) void attn_kernel(
    const float* __restrict__ pair, const float* __restrict__ mask,
    const float* __restrict__ dpos, const float* __restrict__ Q,
    const float* __restrict__ K, const float* __restrict__ w,
    const unsigned short* __restrict__ Wbp, const float* __restrict__ Sh_g,
    const float* __restrict__ cb_g, float* __restrict__ out)
{
    int bi = blockIdx.x;              // b*N + i
    int b = bi >> 9, i = bi & 511;
    int t = threadIdx.x;
    int lane = t & 63, wv = t >> 6;

    __shared__ __align__(16) unsigned short Ap[64 * 136];  // pair tile bf16 [j][p], padded
    __shared__ __align__(16) unsigned short Bw[32 * 136];  // Wb' bf16 [h][p], padded
    __shared__ float biasT[64 * 33];  // raw dots [j][h]; reused as reduce scratch + finals
    __shared__ float mrow[64], rrow[64];
    __shared__ __align__(16) float dl2[2][192];            // delta_pos, double-buffered

    // stage Wb' (once)
    {
        const ushort4* src = (const ushort4*)Wbp;
        #pragma unroll
        for (int s = 0; s < 4; ++s) {
            int f = t + 256 * s;      // 0..1023 ushort4 slots
            int hh = f >> 5, p4 = f & 31;
            ushort4 v = src[f];
            *(ushort4*)&Bw[hh * 136 + p4 * 4] = v;
        }
    }

    int h = t & 31, js = t >> 5;      // softmax mapping: head h, j-slice js (8 slices)
    int g = js, c4 = t & 31;          // staging row-group / col slot

    float qreg[16];
    {
        const float4* qp = (const float4*)(Q + (size_t)bi * cE + h * 16);
        #pragma unroll
        for (int d4 = 0; d4 < 4; ++d4) {
            float4 qv = qp[d4];
            qreg[d4 * 4 + 0] = qv.x; qreg[d4 * 4 + 1] = qv.y;
            qreg[d4 * 4 + 2] = qv.z; qreg[d4 * 4 + 3] = qv.w;
        }
    }
    float Sh_loc = Sh_g[h], cb_loc = cb_g[h];

    float m = -1e30f, l = 0.f, a0 = 0.f, a1 = 0.f, a2 = 0.f;

    const float* pbase = pair + (size_t)bi * cN * cP;
    const float* dbase = dpos + (size_t)bi * cN * 3;
    const float* Kbase = K + (size_t)b * cN * cE;
    const float* wbase = w + (size_t)b * cN * cH;
    const float* mbase = mask + ((size_t)(b * cH + h) * cN + i) * cN;

    // ---- prologue: issue tile-0 prefetches (mask first, pair, dpos) ----
    float4 mk0 = *(const float4*)(mbase + js * 8);
    float4 mk1 = *(const float4*)(mbase + js * 8 + 4);
    float4 pf[8];
    #pragma unroll
    for (int s = 0; s < 8; ++s)
        pf[s] = *(const float4*)(pbase + (size_t)(g + 8 * s) * cP + c4 * 4);
    float4 dpf = {0.f, 0.f, 0.f, 0.f};
    if (t < 48) dpf = *(const float4*)(dbase + t * 4);

    for (int it = 0; it < 8; ++it) {
        int j0 = it * 64;
        int buf = it & 1;

        // ---- A: commit prefetched pair tile to LDS (f32 -> bf16) ----
        #pragma unroll
        for (int s = 0; s < 8; ++s) {
            ushort4 u;
            u.x = f2bf(pf[s].x); u.y = f2bf(pf[s].y);
            u.z = f2bf(pf[s].z); u.w = f2bf(pf[s].w);
            *(ushort4*)&Ap[(g + 8 * s) * 136 + c4 * 4] = u;
        }
        if (t < 48) *(float4*)&dl2[buf][t * 4] = dpf;

        // ---- extract this-tile mask from prefetch regs (already waited) ----
        float mka[8];
        mka[0] = mk0.x; mka[1] = mk0.y; mka[2] = mk0.z; mka[3] = mk0.w;
        mka[4] = mk1.x; mka[5] = mk1.y; mka[6] = mk1.z; mka[7] = mk1.w;

        // ---- B: issue this-tile w loads (L2), BEFORE next-tile HBM prefetch ----
        float wreg[8];
        #pragma unroll
        for (int jj = 0; jj < 8; ++jj)
            wreg[jj] = wbase[(size_t)(j0 + js * 8 + jj) * cH + h];

        __builtin_amdgcn_sched_barrier(0);   // keep w older than prefetch

        // ---- issue next-tile prefetch LAST (stays in flight across barriers) ----
        if (it < 7) {
            mk0 = *(const float4*)(mbase + j0 + 64 + js * 8);
            mk1 = *(const float4*)(mbase + j0 + 64 + js * 8 + 4);
            const float* pb2 = pbase + (size_t)(j0 + 64) * cP;
            #pragma unroll
            for (int s = 0; s < 8; ++s)
                pf[s] = *(const float4*)(pb2 + (size_t)(g + 8 * s) * cP + c4 * 4);
            if (t < 48) dpf = *(const float4*)(dbase + (size_t)(j0 + 64) * 3 + t * 4);
        }

        barrier_nodrain();   // B1: Ap/dl2 visible; prefetch NOT drained

        // ---- C: per-row stats (4-lane shfl finish) + MFMA, same epoch ----
        {
            int r = t >> 2, q = t & 3;
            const uint4* apv = (const uint4*)&Ap[r * 136 + q * 32];
            float s1 = 0.f, s2 = 0.f;
            #pragma unroll
            for (int vv = 0; vv < 4; ++vv) {
                uint4 x = apv[vv];
                unsigned uu[4] = {x.x, x.y, x.z, x.w};
                #pragma unroll
                for (int e = 0; e < 4; ++e) {
                    union { unsigned u; float f; } lo, hi;
                    lo.u = uu[e] << 16;
                    hi.u = uu[e] & 0xffff0000u;
                    s1 += lo.f + hi.f;
                    s2 = fmaf(lo.f, lo.f, s2);
                    s2 = fmaf(hi.f, hi.f, s2);
                }
            }
            s1 += __shfl_xor(s1, 1, 64); s2 += __shfl_xor(s2, 1, 64);
            s1 += __shfl_xor(s1, 2, 64); s2 += __shfl_xor(s2, 2, 64);
            if ((t & 3) == 0) {
                float mu = s1 * (1.0f / cP);
                float var = s2 * (1.0f / cP) - mu * mu;
                mrow[r] = mu;
                rrow[r] = rsqrtf(var + 1e-5f);
            }
        }
        {
            f32x4 acc0 = {0.f, 0.f, 0.f, 0.f}, acc1 = {0.f, 0.f, 0.f, 0.f};
            int arow = wv * 16 + (lane & 15);
            int kq = (lane >> 4) * 8;
            #pragma unroll
            for (int kb = 0; kb < 4; ++kb) {
                int k = kb * 32 + kq;
                bf16x8 af = *(const bf16x8*)&Ap[arow * 136 + k];
                bf16x8 b0 = *(const bf16x8*)&Bw[(lane & 15) * 136 + k];
                bf16x8 b1 = *(const bf16x8*)&Bw[(16 + (lane & 15)) * 136 + k];
                acc0 = __builtin_amdgcn_mfma_f32_16x16x32_bf16(af, b0, acc0, 0, 0, 0);
                acc1 = __builtin_amdgcn_mfma_f32_16x16x32_bf16(af, b1, acc1, 0, 0, 0);
            }
            int crow = wv * 16 + (lane >> 4) * 4;
            int ccol = lane & 15;
            #pragma unroll
            for (int r = 0; r < 4; ++r) {
                biasT[(crow + r) * 33 + ccol] = acc0[r];
                biasT[(crow + r) * 33 + 16 + ccol] = acc1[r];
            }
        }

        barrier_nodrain();   // B2: mrow/rrow/biasT visible; prefetch still in flight

        // ---- D: logits + online softmax + accumulation ----
        #pragma unroll
        for (int jj = 0; jj < 8; ++jj) {
            int jr = js * 8 + jj;
            int j = j0 + jr;
            float bias = rrow[jr] * (biasT[jr * 33 + h] - mrow[jr] * Sh_loc) + cb_loc;
            const float4* kp4 = (const float4*)(Kbase + (size_t)j * cE + h * 16);
            float qk = 0.f;
            #pragma unroll
            for (int d4 = 0; d4 < 4; ++d4) {
                float4 kv = kp4[d4];
                qk = fmaf(qreg[d4 * 4 + 0], kv.x, qk);
                qk = fmaf(qreg[d4 * 4 + 1], kv.y, qk);
                qk = fmaf(qreg[d4 * 4 + 2], kv.z, qk);
                qk = fmaf(qreg[d4 * 4 + 3], kv.w, qk);
            }
            float z = qk + bias + mka[jj];
            float wj = wreg[jj];
            float mn = fmaxf(m, z);
            float sc = __expf(m - mn);
            float p = __expf(z - mn);
            l = l * sc + p;
            float pw = p * wj;
            a0 = fmaf(pw, dl2[buf][jr * 3 + 0], a0 * sc);
            a1 = fmaf(pw, dl2[buf][jr * 3 + 1], a1 * sc);
            a2 = fmaf(pw, dl2[buf][jr * 3 + 2], a2 * sc);
            m = mn;
        }
        // no trailing barrier: next iter's B1 joins logits readers; commit writes
        // only Ap/dl2[buf^1], which logits never reads; mrow/rrow rewritten only
        // after B1 of next tile (all waves past this tile's logits by then).
    }

    // ---- merge 8 js-slices per head, then sum over heads ----
    __syncthreads();       // all logits reads of biasT done before reuse as scratch
    float* red = biasT;    // (h*8+js)*6 records
    red[(h * 8 + js) * 6 + 0] = m;
    red[(h * 8 + js) * 6 + 1] = l;
    red[(h * 8 + js) * 6 + 2] = a0;
    red[(h * 8 + js) * 6 + 3] = a1;
    red[(h * 8 + js) * 6 + 4] = a2;
    __syncthreads();
    for (int s = 4; s >= 1; s >>= 1) {
        if (js < s) {
            float* p1 = &red[(h * 8 + js) * 6];
            float* p2 = &red[(h * 8 + js + s) * 6];
            float m1 = p1[0], m2 = p2[0];
            float mn = fmaxf(m1, m2);
            float s1 = __expf(m1 - mn), s2 = __expf(m2 - mn);
            p1[0] = mn;
            p1[1] = p1[1] * s1 + p2[1] * s2;
            p1[2] = p1[2] * s1 + p2[2] * s2;
            p1[3] = p1[3] * s1 + p2[3] * s2;
            p1[4] = p1[4] * s1 + p2[4] * s2;
        }
        __syncthreads();
    }
    if (js == 0) {
        float linv = 1.0f / red[h * 48 + 1];
        biasT[1536 + h * 3 + 0] = red[h * 48 + 2] * linv;
        biasT[1536 + h * 3 + 1] = red[h * 48 + 3] * linv;
        biasT[1536 + h * 3 + 2] = red[h * 48 + 4] * linv;
    }
    __syncthreads();
    if (t < 3) {
        float s = 0.f;
        #pragma unroll
        for (int hh = 0; hh < cH; ++hh) s += biasT[1536 + hh * 3 + t];
        out[(size_t)bi * 3 + t] = s;
    }
}

// ---------------------------------------------------------------
extern "C" void kernel_launch(void* const* d_in, const int* in_sizes, int n_in,
                              void* d_out, int out_size, void* d_ws, size_t ws_size,
                              hipStream_t stream)
{
    const float* query = (const float*)d_in[0];
    const float* pair  = (const float*)d_in[1];
    const float* amask = (const float*)d_in[2];
    const float* dpos  = (const float*)d_in[3];
    const float* ln_g  = (const float*)d_in[4];
    const float* ln_b  = (const float*)d_in[5];
    const float* Wq    = (const float*)d_in[6];
    const float* Wk    = (const float*)d_in[7];
    const float* Wv    = (const float*)d_in[8];
    const float* pg    = (const float*)d_in[9];
    const float* pb    = (const float*)d_in[10];
    const float* Wb    = (const float*)d_in[11];
    const float* bbv   = (const float*)d_in[12];
    const float* Wf    = (const float*)d_in[13];
    float* out = (float*)d_out;

    char* ws = (char*)d_ws;
    float* xn = (float*)ws;                              // 4 MB
    float* Q  = (float*)(ws + (size_t)4 * 1048576);      // 4 MB
    float* K  = (float*)(ws + (size_t)8 * 1048576);      // 4 MB
    float* w  = (float*)(ws + (size_t)12 * 1048576);     // 256 KB
    unsigned short* Wbp = (unsigned short*)(ws + (size_t)12 * 1048576 + 262144); // 8 KB
    float* Sh  = (float*)(ws + (size_t)12 * 1048576 + 262144 + 8192);
    float* cbh = (float*)(ws + (size_t)12 * 1048576 + 262144 + 8192 + 128);

    ln_query_kernel<<<cB * cN, 256, 0, stream>>>(query, ln_g, ln_b, xn);
    setup_kernel<<<1, 64, 0, stream>>>(Wb, pg, pb, bbv, Wbp, Sh, cbh);
    hipMemsetAsync(w, 0, (size_t)cB * cN * cH * sizeof(float), stream);
    qkv_kernel<<<32 * 24, 256, 0, stream>>>(xn, Wq, Wk, Wv, Wf, Q, K, w);
    attn_kernel<<<cB * cN, 256, 0, stream>>>(pair, amask, dpos, Q, K, w, Wbp, Sh, cbh, out);
}

// Round 3
// 923.464 us; speedup vs baseline: 1.1524x; 1.1524x over previous
//
#include <hip/hip_runtime.h>
#include <hip/hip_bf16.h>
#include <stdint.h>

// Problem constants
constexpr int cB = 4, cN = 512, cE = 512, cH = 32, cP = 128;
// D = 16, SCALING = 0.25 folded into Q at projection epilogue.

typedef __attribute__((ext_vector_type(8))) short bf16x8;
typedef __attribute__((ext_vector_type(4))) float f32x4;

__device__ __forceinline__ unsigned short f2bf(float f) {
    union { float f; unsigned u; } v; v.f = f;
    unsigned u = v.u;
    u += 0x7fffu + ((u >> 16) & 1u);   // RNE
    return (unsigned short)(u >> 16);
}
__device__ __forceinline__ unsigned pack2bf(float lo, float hi) {
    return (unsigned)f2bf(lo) | ((unsigned)f2bf(hi) << 16);
}

// Barrier that drains everything (tile boundary: landing zone must be complete).
#define BAR_VM() do { \
    asm volatile("s_waitcnt vmcnt(0) lgkmcnt(0)" ::: "memory"); \
    __builtin_amdgcn_sched_barrier(0); \
    __builtin_amdgcn_s_barrier(); \
    __builtin_amdgcn_sched_barrier(0); } while (0)

// Barrier that fences LDS only: in-flight global_load_lds stays outstanding.
#define BAR_LGKM() do { \
    asm volatile("s_waitcnt lgkmcnt(0)" ::: "memory"); \
    __builtin_amdgcn_sched_barrier(0); \
    __builtin_amdgcn_s_barrier(); \
    __builtin_amdgcn_sched_barrier(0); } while (0)

// Zero-VGPR global->LDS copy, 16B per lane. lds ptr must be wave-uniform.
__device__ __forceinline__ void gl_lds16(const float* g, float* l) {
    __builtin_amdgcn_global_load_lds(
        (const __attribute__((address_space(1))) void*)g,
        (__attribute__((address_space(3))) void*)l, 16, 0, 0);
}

// ---------------- Kernel 1: LayerNorm(query) -> xn (f32) ----------------
__global__ __launch_bounds__(256) void ln_query_kernel(
    const float* __restrict__ q, const float* __restrict__ g,
    const float* __restrict__ b, float* __restrict__ xn)
{
    int row = blockIdx.x;          // 0..B*N-1
    int t = threadIdx.x;           // 256
    const float* xr = q + (size_t)row * cE;
    float2 v = *(const float2*)(xr + t * 2);
    float s = v.x + v.y;
    float ss = v.x * v.x + v.y * v.y;
    #pragma unroll
    for (int o = 32; o > 0; o >>= 1) {
        s  += __shfl_down(s, o, 64);
        ss += __shfl_down(ss, o, 64);
    }
    __shared__ float red[8];
    int wv = t >> 6, ln = t & 63;
    if (ln == 0) { red[wv] = s; red[wv + 4] = ss; }
    __syncthreads();
    if (t == 0) {
        float S = red[0] + red[1] + red[2] + red[3];
        float SS = red[4] + red[5] + red[6] + red[7];
        float mu = S * (1.0f / cE);
        float var = SS * (1.0f / cE) - mu * mu;
        red[0] = mu; red[1] = rsqrtf(var + 1e-5f);
    }
    __syncthreads();
    float mu = red[0], rs = red[1];
    float2 gg = *(const float2*)(g + t * 2);
    float2 bb2 = *(const float2*)(b + t * 2);
    float2 o2;
    o2.x = (v.x - mu) * rs * gg.x + bb2.x;
    o2.y = (v.y - mu) * rs * gg.y + bb2.y;
    *(float2*)(xn + (size_t)row * cE + t * 2) = o2;
}

// ---------------- Kernel 2: setup Wb' (bf16), S_h, cb_h (256-thread) ----------------
__global__ __launch_bounds__(256) void setup_kernel(
    const float* __restrict__ Wb, const float* __restrict__ pg,
    const float* __restrict__ pb, const float* __restrict__ bbv,
    unsigned short* __restrict__ Wbp, float* __restrict__ Sh,
    float* __restrict__ cbh)
{
    int t = threadIdx.x;
    int h = t >> 3, s8 = t & 7;            // 8 lanes per head, 16 p each
    const float* wrow = Wb + h * cP + s8 * 16;
    const float* pgp = pg + s8 * 16;
    const float* pbp = pb + s8 * 16;
    unsigned short* wdst = Wbp + h * cP + s8 * 16;
    float s = 0.f, c = 0.f;
    #pragma unroll
    for (int e = 0; e < 16; ++e) {
        float wv = wrow[e];
        float wp = wv * pgp[e];
        s += wp;
        c = fmaf(pbp[e], wv, c);
        wdst[e] = f2bf(wp);
    }
    s += __shfl_xor(s, 1, 64); c += __shfl_xor(c, 1, 64);
    s += __shfl_xor(s, 2, 64); c += __shfl_xor(c, 2, 64);
    s += __shfl_xor(s, 4, 64); c += __shfl_xor(c, 4, 64);
    if (s8 == 0) { Sh[h] = s; cbh[h] = c + bbv[h]; }
}

// ------------- Kernel 3: Q/K projections (fp32 GEMM) + w from V tile -------------
__global__ __launch_bounds__(256) void qkv_kernel(
    const float* __restrict__ xn,
    const float* __restrict__ Wq, const float* __restrict__ Wk,
    const float* __restrict__ Wv, const float* __restrict__ Wf,
    float* __restrict__ Q, float* __restrict__ K, float* __restrict__ w)
{
    int mtile = blockIdx.x & 31;      // 32 tiles of 64 rows
    int ntile = blockIdx.x >> 5;      // 24 tiles of 64 cols
    int mat = ntile >> 3;             // 0=Q 1=K 2=V
    int ncol0 = (ntile & 7) * 64;
    const float* W = (mat == 0) ? Wq : ((mat == 1) ? Wk : Wv);
    int rm = mtile * 64;
    int t = threadIdx.x;
    int tm = t >> 4, tn = t & 15;     // 16x16 thread grid, 4x4 micro-tile

    __shared__ float As[32][68];      // [k][m]
    __shared__ float Bs[32][68];      // [k][n]
    float acc[4][4];
    #pragma unroll
    for (int i = 0; i < 4; ++i)
        #pragma unroll
        for (int j = 0; j < 4; ++j) acc[i][j] = 0.f;

    for (int k0 = 0; k0 < cE; k0 += 32) {
        #pragma unroll
        for (int s = 0; s < 2; ++s) {
            int f = t + 256 * s;      // 0..511 float4 slots
            int row = f >> 3, kq = f & 7;
            float4 v = *(const float4*)(xn + (size_t)(rm + row) * cE + k0 + kq * 4);
            As[kq * 4 + 0][row] = v.x; As[kq * 4 + 1][row] = v.y;
            As[kq * 4 + 2][row] = v.z; As[kq * 4 + 3][row] = v.w;
            float4 u = *(const float4*)(W + (size_t)(ncol0 + row) * cE + k0 + kq * 4);
            Bs[kq * 4 + 0][row] = u.x; Bs[kq * 4 + 1][row] = u.y;
            Bs[kq * 4 + 2][row] = u.z; Bs[kq * 4 + 3][row] = u.w;
        }
        __syncthreads();
        #pragma unroll
        for (int kk = 0; kk < 32; ++kk) {
            float a[4], bv[4];
            #pragma unroll
            for (int i = 0; i < 4; ++i) a[i] = As[kk][tm * 4 + i];
            #pragma unroll
            for (int j = 0; j < 4; ++j) bv[j] = Bs[kk][tn * 4 + j];
            #pragma unroll
            for (int i = 0; i < 4; ++i)
                #pragma unroll
                for (int j = 0; j < 4; ++j) acc[i][j] = fmaf(a[i], bv[j], acc[i][j]);
        }
        __syncthreads();
    }

    if (mat < 2) {
        float scale = (mat == 0) ? 0.25f : 1.0f;
        float* dst = (mat == 0) ? Q : K;
        #pragma unroll
        for (int i = 0; i < 4; ++i) {
            int r = rm + tm * 4 + i;
            float4 o;
            o.x = acc[i][0] * scale; o.y = acc[i][1] * scale;
            o.z = acc[i][2] * scale; o.w = acc[i][3] * scale;
            *(float4*)(dst + (size_t)r * cE + ncol0 + tn * 4) = o;
        }
    } else {
        int col0 = ncol0 + tn * 4;
        int h = col0 >> 4;
        float wf[4];
        #pragma unroll
        for (int j = 0; j < 4; ++j) wf[j] = Wf[col0 + j];
        #pragma unroll
        for (int i = 0; i < 4; ++i) {
            int r = rm + tm * 4 + i;
            float part = 0.f;
            #pragma unroll
            for (int j = 0; j < 4; ++j) part = fmaf(acc[i][j], wf[j], part);
            atomicAdd(&w[(size_t)r * cH + h], part);
        }
    }
}

// ------------- Kernel 4: fused bias-GEMM + attention + force (per (b,i)) -------------
// v4: pair prefetch via global_load_lds (ZERO prefetch VGPRs -> no spills).
//   32-j tiles (16 tiles). Per tile:
//     A: ds_write dpos; BAR_VM (landing zone t complete);
//     convert+stats: Lf32 -> normalized bf16 Ap (8-lane shfl stats);  BAR_LGKM;
//     issue t+1 loads (load_lds pair; mask/w/dpos regs);
//     MFMA (per-wave 16x16 quadrant, acc stays in REGISTERS);
//     logits straight from acc (no biasT LDS, no 3rd barrier).
//   2 barriers/tile; only the tile-top one drains vmcnt. LDS ~34.8 KB -> 4 blocks/CU.
__global__ __launch_bounds__(256, 4) void attn_kernel(
    const float* __restrict__ pair, const float* __restrict__ mask,
    const float* __restrict__ dpos, const float* __restrict__ Q,
    const float* __restrict__ K, const float* __restrict__ w,
    const unsigned short* __restrict__ Wbp, const float* __restrict__ Sh_g,
    const float* __restrict__ cb_g, float* __restrict__ out)
{
    int bi = blockIdx.x;              // b*N + i
    int b = bi >> 9, i = bi & 511;
    int t = threadIdx.x;
    int lane = t & 63, wv = t >> 6;

    __shared__ __align__(16) float Lf32[4096];             // 16 KB pair f32 landing; reused as merge scratch
    __shared__ __align__(16) unsigned short Ap[32 * 136];  // normalized pair bf16 [j][p], padded
    __shared__ __align__(16) unsigned short Bw[32 * 136];  // Wb' bf16 [h][p], padded
    __shared__ __align__(16) float dl[2][128];             // delta_pos, double-buffered

    // stage Wb' (once)
    {
        const ushort4* src = (const ushort4*)Wbp;
        #pragma unroll
        for (int s = 0; s < 4; ++s) {
            int f = t + 256 * s;      // 0..1023 ushort4 slots
            int hh = f >> 5, p4 = f & 31;
            ushort4 v = src[f];
            *(ushort4*)&Bw[hh * 136 + p4 * 4] = v;
        }
    }

    // wave-quadrant ownership: wave wv computes C[j16:j16+16][h16:h16+16];
    // its lanes consume exactly that quadrant in the logits phase.
    int j16 = (wv & 1) * 16, h16 = (wv >> 1) * 16;
    int q4 = lane >> 4;               // 0..3: j sub-slice within quadrant
    int jb = j16 + q4 * 4;            // thread's j base within tile (4 rows)
    int hT = h16 + (lane & 15);       // thread's head

    float qreg[16];
    {
        const float4* qp = (const float4*)(Q + (size_t)bi * cE + hT * 16);
        #pragma unroll
        for (int d4 = 0; d4 < 4; ++d4) {
            float4 qv = qp[d4];
            qreg[d4 * 4 + 0] = qv.x; qreg[d4 * 4 + 1] = qv.y;
            qreg[d4 * 4 + 2] = qv.z; qreg[d4 * 4 + 3] = qv.w;
        }
    }
    float cb_loc = cb_g[hT];

    float m = -1e30f, l = 0.f, a0 = 0.f, a1 = 0.f, a2 = 0.f;

    const float* pbase = pair + (size_t)bi * cN * cP;
    const float* dbase = dpos + (size_t)bi * cN * 3;
    const float* Kbase = K + (size_t)b * cN * cE;
    const float* wbase = w + (size_t)b * cN * cH;
    const float* mbase = mask + ((size_t)(b * cH + hT) * cN + i) * cN;

    // ---- prologue: tile-0 operands ----
    float4 mka = *(const float4*)(mbase + jb);
    float wcur[4];
    #pragma unroll
    for (int jj = 0; jj < 4; ++jj)
        wcur[jj] = wbase[(size_t)(jb + jj) * cH + hT];
    float4 dpf = {0.f, 0.f, 0.f, 0.f};
    if (t < 24) dpf = *(const float4*)(dbase + t * 4);
    #pragma unroll
    for (int s = 0; s < 4; ++s) {
        int chunk = wv * 4 + s;
        gl_lds16(pbase + chunk * 256 + lane * 4, &Lf32[chunk * 256]);
    }

    int buf = 0;
    for (int it = 0; it < 16; ++it) {
        const int j0 = it * 32;

        // ---- A: commit dpos tile (from regs loaded last iter) ----
        if (t < 24) *(float4*)&dl[buf][t * 4] = dpf;

        BAR_VM();   // landing zone for tile `it` complete; dl visible

        // ---- convert + stats: Lf32 -> normalized bf16 Ap ----
        {
            int r = t >> 3, sub = t & 7;          // 8 lanes per row, 16 floats each
            const float4* lr = (const float4*)&Lf32[r * 128 + sub * 16];
            float4 x0 = lr[0], x1 = lr[1], x2 = lr[2], x3 = lr[3];
            float s1 = x0.x + x0.y + x0.z + x0.w + x1.x + x1.y + x1.z + x1.w
                     + x2.x + x2.y + x2.z + x2.w + x3.x + x3.y + x3.z + x3.w;
            float s2 = 0.f;
            s2 = fmaf(x0.x, x0.x, s2); s2 = fmaf(x0.y, x0.y, s2);
            s2 = fmaf(x0.z, x0.z, s2); s2 = fmaf(x0.w, x0.w, s2);
            s2 = fmaf(x1.x, x1.x, s2); s2 = fmaf(x1.y, x1.y, s2);
            s2 = fmaf(x1.z, x1.z, s2); s2 = fmaf(x1.w, x1.w, s2);
            s2 = fmaf(x2.x, x2.x, s2); s2 = fmaf(x2.y, x2.y, s2);
            s2 = fmaf(x2.z, x2.z, s2); s2 = fmaf(x2.w, x2.w, s2);
            s2 = fmaf(x3.x, x3.x, s2); s2 = fmaf(x3.y, x3.y, s2);
            s2 = fmaf(x3.z, x3.z, s2); s2 = fmaf(x3.w, x3.w, s2);
            s1 += __shfl_xor(s1, 1, 64); s2 += __shfl_xor(s2, 1, 64);
            s1 += __shfl_xor(s1, 2, 64); s2 += __shfl_xor(s2, 2, 64);
            s1 += __shfl_xor(s1, 4, 64); s2 += __shfl_xor(s2, 4, 64);
            float mu = s1 * (1.0f / cP);
            float rs_ = rsqrtf(s2 * (1.0f / cP) - mu * mu + 1e-5f);
            uint4 o0, o1;
            o0.x = pack2bf((x0.x - mu) * rs_, (x0.y - mu) * rs_);
            o0.y = pack2bf((x0.z - mu) * rs_, (x0.w - mu) * rs_);
            o0.z = pack2bf((x1.x - mu) * rs_, (x1.y - mu) * rs_);
            o0.w = pack2bf((x1.z - mu) * rs_, (x1.w - mu) * rs_);
            o1.x = pack2bf((x2.x - mu) * rs_, (x2.y - mu) * rs_);
            o1.y = pack2bf((x2.z - mu) * rs_, (x2.w - mu) * rs_);
            o1.z = pack2bf((x3.x - mu) * rs_, (x3.y - mu) * rs_);
            o1.w = pack2bf((x3.z - mu) * rs_, (x3.w - mu) * rs_);
            *(uint4*)&Ap[r * 136 + sub * 16] = o0;
            *(uint4*)&Ap[r * 136 + sub * 16 + 8] = o1;
        }

        BAR_LGKM();   // Ap visible; Lf32 free; in-flight vmem NOT drained

        // ---- issue tile it+1 loads (fly across rest of tile: MFMA + logits) ----
        float4 mk_n = {0.f, 0.f, 0.f, 0.f};
        float wn0 = 0.f, wn1 = 0.f, wn2 = 0.f, wn3 = 0.f;
        if (it < 15) {
            const float* slab = pbase + (size_t)(j0 + 32) * cP;
            #pragma unroll
            for (int s = 0; s < 4; ++s) {
                int chunk = wv * 4 + s;
                gl_lds16(slab + chunk * 256 + lane * 4, &Lf32[chunk * 256]);
            }
            mk_n = *(const float4*)(mbase + j0 + 32 + jb);
            wn0 = wbase[(size_t)(j0 + 32 + jb + 0) * cH + hT];
            wn1 = wbase[(size_t)(j0 + 32 + jb + 1) * cH + hT];
            wn2 = wbase[(size_t)(j0 + 32 + jb + 2) * cH + hT];
            wn3 = wbase[(size_t)(j0 + 32 + jb + 3) * cH + hT];
            if (t < 24) dpf = *(const float4*)(dbase + (size_t)(j0 + 32) * 3 + t * 4);
        }

        // ---- MFMA: per-wave 16x16 quadrant, acc in registers ----
        f32x4 acc = {0.f, 0.f, 0.f, 0.f};
        {
            int ar = (j16 + (lane & 15)) * 136;
            int br = (h16 + (lane & 15)) * 136;
            int kq = q4 * 8;
            #pragma unroll
            for (int kb = 0; kb < 4; ++kb) {
                int k = kb * 32 + kq;
                bf16x8 af = *(const bf16x8*)&Ap[ar + k];
                bf16x8 bb_ = *(const bf16x8*)&Bw[br + k];
                acc = __builtin_amdgcn_mfma_f32_16x16x32_bf16(af, bb_, acc, 0, 0, 0);
            }
        }

        // ---- logits + online softmax, bias straight from acc ----
        #pragma unroll
        for (int jj = 0; jj < 4; ++jj) {
            int jr = jb + jj;
            int j = j0 + jr;
            float bias = acc[jj] + cb_loc;
            const float4* kp4 = (const float4*)(Kbase + (size_t)j * cE + hT * 16);
            float qk = 0.f;
            #pragma unroll
            for (int d4 = 0; d4 < 4; ++d4) {
                float4 kv = kp4[d4];
                qk = fmaf(qreg[d4 * 4 + 0], kv.x, qk);
                qk = fmaf(qreg[d4 * 4 + 1], kv.y, qk);
                qk = fmaf(qreg[d4 * 4 + 2], kv.z, qk);
                qk = fmaf(qreg[d4 * 4 + 3], kv.w, qk);
            }
            float mkv = (jj == 0) ? mka.x : (jj == 1) ? mka.y : (jj == 2) ? mka.z : mka.w;
            float z = qk + bias + mkv;
            float wj = wcur[jj];
            float mn = fmaxf(m, z);
            float sc = __expf(m - mn);
            float p = __expf(z - mn);
            l = l * sc + p;
            float pw = p * wj;
            a0 = fmaf(pw, dl[buf][jr * 3 + 0], a0 * sc);
            a1 = fmaf(pw, dl[buf][jr * 3 + 1], a1 * sc);
            a2 = fmaf(pw, dl[buf][jr * 3 + 2], a2 * sc);
            m = mn;
        }
        if (it < 15) {
            mka = mk_n;
            wcur[0] = wn0; wcur[1] = wn1; wcur[2] = wn2; wcur[3] = wn3;
        }
        buf ^= 1;
        // no trailing barrier: next A writes dl[buf^1]; next BAR_VM separates
        // Ap/Lf32 rewrites from this tile's readers.
    }

    // ---- merge 8 slices per head (Lf32 as scratch), then sum over heads ----
    float* red = Lf32;
    int slice = (wv & 1) * 4 + q4;    // (hT, slice) bijective over 32x8
    red[(hT * 8 + slice) * 6 + 0] = m;
    red[(hT * 8 + slice) * 6 + 1] = l;
    red[(hT * 8 + slice) * 6 + 2] = a0;
    red[(hT * 8 + slice) * 6 + 3] = a1;
    red[(hT * 8 + slice) * 6 + 4] = a2;
    __syncthreads();
    for (int s = 4; s >= 1; s >>= 1) {
        if (slice < s) {
            float* p1 = &red[(hT * 8 + slice) * 6];
            float* p2 = &red[(hT * 8 + slice + s) * 6];
            float m1 = p1[0], m2 = p2[0];
            float mn = fmaxf(m1, m2);
            float s1 = __expf(m1 - mn), s2 = __expf(m2 - mn);
            p1[0] = mn;
            p1[1] = p1[1] * s1 + p2[1] * s2;
            p1[2] = p1[2] * s1 + p2[2] * s2;
            p1[3] = p1[3] * s1 + p2[3] * s2;
            p1[4] = p1[4] * s1 + p2[4] * s2;
        }
        __syncthreads();
    }
    if (slice == 0) {
        float linv = 1.0f / red[hT * 48 + 1];
        red[2048 + hT * 3 + 0] = red[hT * 48 + 2] * linv;
        red[2048 + hT * 3 + 1] = red[hT * 48 + 3] * linv;
        red[2048 + hT * 3 + 2] = red[hT * 48 + 4] * linv;
    }
    __syncthreads();
    if (t < 3) {
        float s = 0.f;
        #pragma unroll
        for (int hh = 0; hh < cH; ++hh) s += red[2048 + hh * 3 + t];
        out[(size_t)bi * 3 + t] = s;
    }
}

// ---------------------------------------------------------------
extern "C" void kernel_launch(void* const* d_in, const int* in_sizes, int n_in,
                              void* d_out, int out_size, void* d_ws, size_t ws_size,
                              hipStream_t stream)
{
    const float* query = (const float*)d_in[0];
    const float* pair  = (const float*)d_in[1];
    const float* amask = (const float*)d_in[2];
    const float* dpos  = (const float*)d_in[3];
    const float* ln_g  = (const float*)d_in[4];
    const float* ln_b  = (const float*)d_in[5];
    const float* Wq    = (const float*)d_in[6];
    const float* Wk    = (const float*)d_in[7];
    const float* Wv    = (const float*)d_in[8];
    const float* pg    = (const float*)d_in[9];
    const float* pb    = (const float*)d_in[10];
    const float* Wb    = (const float*)d_in[11];
    const float* bbv   = (const float*)d_in[12];
    const float* Wf    = (const float*)d_in[13];
    float* out = (float*)d_out;

    char* ws = (char*)d_ws;
    float* xn = (float*)ws;                              // 4 MB
    float* Q  = (float*)(ws + (size_t)4 * 1048576);      // 4 MB
    float* K  = (float*)(ws + (size_t)8 * 1048576);      // 4 MB
    float* w  = (float*)(ws + (size_t)12 * 1048576);     // 256 KB
    unsigned short* Wbp = (unsigned short*)(ws + (size_t)12 * 1048576 + 262144); // 8 KB
    float* Sh  = (float*)(ws + (size_t)12 * 1048576 + 262144 + 8192);
    float* cbh = (float*)(ws + (size_t)12 * 1048576 + 262144 + 8192 + 128);

    ln_query_kernel<<<cB * cN, 256, 0, stream>>>(query, ln_g, ln_b, xn);
    setup_kernel<<<1, 256, 0, stream>>>(Wb, pg, pb, bbv, Wbp, Sh, cbh);
    hipMemsetAsync(w, 0, (size_t)cB * cN * cH * sizeof(float), stream);
    qkv_kernel<<<32 * 24, 256, 0, stream>>>(xn, Wq, Wk, Wv, Wf, Q, K, w);
    attn_kernel<<<cB * cN, 256, 0, stream>>>(pair, amask, dpos, Q, K, w, Wbp, Sh, cbh, out);
}